// Round 1
// baseline (158.115 us; speedup 1.0000x reference)
//
#include <hip/hip_runtime.h>

// MPS chain contraction, MI355X/gfx950.
// N=1024 sites, B=256 batch, D=16 bond, d=2 physical, C=10 classes.
//
// out[b,o] = e0^T (prod_{n<512} A_n,b) Aout[o] (prod_{n>=512} A_n,b) e0
// with A_n,b = x[n,b,0]*T(n,:,:,0) + x[n,b,1]*T(n,:,:,1).
//
// Phase 1: 64 segments of 16 sites; lane = (seg, batch, row j) runs a
//          16-float row-vector chain v <- x0*(v@T0) + x1*(v@T1).
//          T[n] is wave-uniform -> scalar loads; no LDS, no barriers.
// Phase 2: per batch, serial segment matvecs via 16-lane shuffles, then
//          the tiny bilinear output contraction.

#define NSITES 1024
#define BATCH  256
#define BD     16
#define NSEG   64
#define SEGLEN (NSITES / NSEG)   // 16 sites per segment
#define NCLS   10

__global__ __launch_bounds__(256) void seg_prod_kernel(
    const float* __restrict__ x,        // (N, B, 2)
    const float* __restrict__ tensor,   // (N, 16, 16, 2)
    float* __restrict__ M)              // (NSEG, B, 16, 16) segment products
{
    const int s  = blockIdx.x;          // segment 0..63
    const int bg = blockIdx.y;          // batch group 0..15
    const int t  = threadIdx.x;         // 0..255
    const int bs = t & 15;              // batch within group (low bits -> coalesced x)
    const int j  = t >> 4;              // row of the segment product
    const int b  = bg * 16 + bs;

    // v = row j of running product, init = e_j (P = I)
    float v[BD];
#pragma unroll
    for (int r = 0; r < BD; ++r) v[r] = (r == j) ? 1.0f : 0.0f;

    const int n0 = s * SEGLEN;
    for (int n = n0; n < n0 + SEGLEN; ++n) {
        const float2 xv = *(const float2*)(x + (size_t)(n * BATCH + b) * 2);
        // T[n] viewed as float2[k*16 + r] = (T0[k][r], T1[k][r]); wave-uniform.
        const float2* __restrict__ Tn = (const float2*)(tensor + (size_t)n * 512);

        float2 u[BD];
#pragma unroll
        for (int r = 0; r < BD; ++r) { u[r].x = 0.0f; u[r].y = 0.0f; }

#pragma unroll
        for (int k = 0; k < BD; ++k) {
            const float vk = v[k];
#pragma unroll
            for (int r = 0; r < BD; ++r) {
                const float2 tv = Tn[k * BD + r];
                u[r].x = __builtin_fmaf(vk, tv.x, u[r].x);
                u[r].y = __builtin_fmaf(vk, tv.y, u[r].y);
            }
        }
#pragma unroll
        for (int r = 0; r < BD; ++r)
            v[r] = __builtin_fmaf(xv.x, u[r].x, xv.y * u[r].y);
    }

    float* __restrict__ Mout = M + (((size_t)s * BATCH + b) * BD + j) * BD;
#pragma unroll
    for (int r = 0; r < BD; ++r) Mout[r] = v[r];
}

__global__ __launch_bounds__(256) void combine_kernel(
    const float* __restrict__ M,      // (NSEG, B, 16, 16)
    const float* __restrict__ Aout,   // (C, 16, 16)
    float* __restrict__ out)          // (B, C)
{
    const int t  = threadIdx.x;
    const int r  = t & 15;            // lane within 16-lane group
    const int bs = t >> 4;
    const int b  = blockIdx.x * 16 + bs;

    // Left half: vL = e0^T M_0 M_1 ... M_31   (thread r holds vL[r])
    float vl = (r == 0) ? 1.0f : 0.0f;
    for (int s = 0; s < NSEG / 2; ++s) {
        const float* __restrict__ Ms = M + (((size_t)s * BATCH + b) * BD) * BD;
        float acc = 0.0f;
#pragma unroll
        for (int k = 0; k < BD; ++k) {
            const float vk = __shfl(vl, k, 16);
            acc = __builtin_fmaf(vk, Ms[k * BD + r], acc);
        }
        vl = acc;
    }

    // Right half: vR = M_32 (M_33 (... (M_63 e0)))  (thread r holds vR[r])
    float vr = (r == 0) ? 1.0f : 0.0f;
    for (int s = NSEG - 1; s >= NSEG / 2; --s) {
        const float* __restrict__ Ms = M + (((size_t)s * BATCH + b) * BD) * BD;
        float acc = 0.0f;
#pragma unroll
        for (int k = 0; k < BD; ++k) {
            const float uk = __shfl(vr, k, 16);
            acc = __builtin_fmaf(Ms[r * BD + k], uk, acc);
        }
        vr = acc;
    }

    // Gather full vR into each lane
    float vrf[BD];
#pragma unroll
    for (int k = 0; k < BD; ++k) vrf[k] = __shfl(vr, k, 16);

    // out[b,o] = sum_l vL[l] * (Aout[o][l][:] . vR)   (thread r does l = r)
    float acc[NCLS];
#pragma unroll
    for (int o = 0; o < NCLS; ++o) {
        float ts = 0.0f;
#pragma unroll
        for (int k = 0; k < BD; ++k)
            ts = __builtin_fmaf(Aout[((size_t)o * BD + r) * BD + k], vrf[k], ts);
        acc[o] = vl * ts;
    }
#pragma unroll
    for (int off = 8; off > 0; off >>= 1) {
#pragma unroll
        for (int o = 0; o < NCLS; ++o)
            acc[o] += __shfl_xor(acc[o], off, 16);
    }
    if (r == 0) {
#pragma unroll
        for (int o = 0; o < NCLS; ++o) out[(size_t)b * NCLS + o] = acc[o];
    }
}

extern "C" void kernel_launch(void* const* d_in, const int* in_sizes, int n_in,
                              void* d_out, int out_size, void* d_ws, size_t ws_size,
                              hipStream_t stream)
{
    const float* x      = (const float*)d_in[0];   // 1024*256*2
    const float* tensor = (const float*)d_in[1];   // 1024*16*16*2
    const float* Aout   = (const float*)d_in[2];   // 10*16*16
    float* out = (float*)d_out;                    // 256*10
    float* M   = (float*)d_ws;                     // 64*256*256 floats = 16 MB

    dim3 g1(NSEG, BATCH / 16);
    seg_prod_kernel<<<g1, 256, 0, stream>>>(x, tensor, M);
    combine_kernel<<<BATCH / 16, 256, 0, stream>>>(M, Aout, out);
}